// Round 12
// baseline (376.597 us; speedup 1.0000x reference)
//
#include <hip/hip_runtime.h>
#include <stdint.h>

typedef unsigned short u16;
typedef short bf16x8 __attribute__((ext_vector_type(8)));
typedef float f32x4 __attribute__((ext_vector_type(4)));

#define MFMA16(a, b, c) __builtin_amdgcn_mfma_f32_16x16x32_bf16((a), (b), (c), 0, 0, 0)

static __device__ __forceinline__ float bfu2f(u16 u) {
  union { unsigned int i; float f; } z; z.i = ((unsigned int)u) << 16; return z.f;
}
static __device__ __forceinline__ u16 f2bfu(float f) {
  union { float f; unsigned int i; } z; z.f = f;
  unsigned int i = z.i;
  return (u16)((i + 0x7fffu + ((i >> 16) & 1u)) >> 16);
}

__device__ __forceinline__ void gload_lds16(const void* g, void* l) {
  __builtin_amdgcn_global_load_lds((const __attribute__((address_space(1))) void*)g,
                                   (__attribute__((address_space(3))) void*)l, 16, 0, 0);
}

// ---------------- prep: LayerNorm || qkv-weight cvt
// blocks [0,16384): ln; [16384,17920): cvt qkv_w.
__global__ __launch_bounds__(256) void prep_kernel(
    const float* __restrict__ x, const float* __restrict__ lw,
    const float* __restrict__ lb, u16* __restrict__ xn,
    const float* __restrict__ qkvw, u16* __restrict__ QKVW) {
  int blk = blockIdx.x;
  int t = threadIdx.x;
  if (blk < 16384) {  // ---- LayerNorm
    int row = blk;
    const float4* xr = (const float4*)(x + (size_t)row * 1024);
    float4 v = xr[t];
    float s = v.x + v.y + v.z + v.w;
    float ss = v.x * v.x + v.y * v.y + v.z * v.z + v.w * v.w;
#pragma unroll
    for (int m = 1; m < 64; m <<= 1) { s += __shfl_xor(s, m); ss += __shfl_xor(ss, m); }
    __shared__ float sb[4], ssb[4];
    int lane = t & 63, wvi = t >> 6;
    if (lane == 0) { sb[wvi] = s; ssb[wvi] = ss; }
    __syncthreads();
    s = sb[0] + sb[1] + sb[2] + sb[3];
    ss = ssb[0] + ssb[1] + ssb[2] + ssb[3];
    float mu = s * (1.0f / 1024.0f);
    float var = ss * (1.0f / 1024.0f) - mu * mu;
    float rstd = rsqrtf(var + 1e-5f);
    float4 wv4 = ((const float4*)lw)[t];
    float4 bv4 = ((const float4*)lb)[t];
    ushort4 o;
    o.x = f2bfu((v.x - mu) * rstd * wv4.x + bv4.x);
    o.y = f2bfu((v.y - mu) * rstd * wv4.y + bv4.y);
    o.z = f2bfu((v.z - mu) * rstd * wv4.z + bv4.z);
    o.w = f2bfu((v.w - mu) * rstd * wv4.w + bv4.w);
    ((ushort4*)xn)[(size_t)row * 256 + t] = o;
  } else {  // ---- f32->bf16 cvt of qkv_w (786432 float4)
    int idx = (blk - 16384) * 256 + t;
    for (int i = idx; i < 786432; i += 393216) {
      float4 v = ((const float4*)qkvw)[i];
      ushort4 o;
      o.x = f2bfu(v.x); o.y = f2bfu(v.y); o.z = f2bfu(v.z); o.w = f2bfu(v.w);
      ((ushort4*)QKVW)[i] = o;
    }
  }
}

// --------------------------------------------------- GEMM  C = A @ Bw^T + bias
// m201-style 8-phase schedule (round-7 verified-best form): BM=BN=256, BK=64,
// 8 waves (2Mx4N), double-buffered LDS, counted vmcnt(6) once per K-tile.
// Bijective XCD swizzle. MODE 1: f32 out; MODE 2: qkv scatter (V transposed)
// + fused landmark pooling. MODE 2 blockIdx.z==1 blocks do independent
// side-work (proj_w cvt / gamma^T / b2) to fill ragged CU tail time.
template <int MODE>
__global__ __launch_bounds__(512, 2) void gemm_bt(
    const u16* __restrict__ A, const u16* __restrict__ Bw,
    const float* __restrict__ bias,
    float* __restrict__ Cf, u16* __restrict__ Cb,
    u16* __restrict__ Qo, u16* __restrict__ Ko, u16* __restrict__ Vo,
    float* __restrict__ qlmf, u16* __restrict__ qlmb,
    float* __restrict__ klmf, u16* __restrict__ klmb,
    const float* __restrict__ projw, u16* __restrict__ PW,
    const float* __restrict__ G, u16* __restrict__ GT,
    const float* __restrict__ gb, const float* __restrict__ pb,
    float* __restrict__ b2,
    int M, int N, int K) {
  __shared__ __attribute__((aligned(16))) u16 As[2][16384];  // [256][64] bf16
  __shared__ __attribute__((aligned(16))) u16 Bs[2][16384];  // [256][64] bf16
  int tid = threadIdx.x;
  int lane = tid & 63;
  int w = tid >> 6;            // 0..7
  int wr = w >> 2, wc = w & 3; // wave grid 2 (M) x 4 (N)
  int r16 = lane & 15, hi = lane >> 4;
  int l8 = lane >> 3, li = lane & 7;

  if (MODE == 2 && blockIdx.z == 1) {
    // ---- side work: e = flat extra-block id.
    int e = blockIdx.y * 12 + blockIdx.x;
    if (e < 512) {  // proj_w f32->bf16 (262144 float4)
      int i = e * 512 + tid;
      float4 v = ((const float4*)projw)[i];
      ushort4 o;
      o.x = f2bfu(v.x); o.y = f2bfu(v.y); o.z = f2bfu(v.z); o.w = f2bfu(v.w);
      ((ushort4*)PW)[i] = o;
    } else if (e < 640) {  // gamma^T: 2 tiles of 64x64 per block
      float (*tt)[68] = (float (*)[68])As;  // 128x68 f32 = 34.8 KB scratch
      int half = tid >> 8;                  // which tile
      int t2 = tid & 255;
      int tile = (e - 512) * 2 + half;
      int tr = (tile >> 4) * 64, tc = (tile & 15) * 64;
      int l = t2 & 63, y = t2 >> 6;
      for (int r = y; r < 64; r += 4)
        tt[half * 64 + r][l] = G[(size_t)(tr + r) * 1024 + tc + l];
      __syncthreads();
      for (int rr = y; rr < 64; rr += 4)
        GT[(size_t)(tc + rr) * 1024 + tr + l] = f2bfu(tt[half * 64 + l][rr]);
    } else if (e < 642) {  // b2 = proj_w @ gamma_b + proj_b
      int i = (e - 640) * 512 + tid;
      const float4* pr = (const float4*)(projw + (size_t)i * 1024);
      const float4* g4 = (const float4*)gb;
      float s = 0.f;
      for (int k = 0; k < 256; ++k) {
        float4 a = pr[k], b = g4[k];
        s += a.x * b.x + a.y * b.y + a.z * b.z + a.w * b.w;
      }
      b2[i] = s + pb[i];
    }
    return;
  }

  int nwg = gridDim.x * gridDim.y;
  int flat = blockIdx.y * gridDim.x + blockIdx.x;
  int q8 = nwg >> 3;
  int swz = (flat & 7) * q8 + (flat >> 3);
  int bx = swz % gridDim.x, by = swz / gridDim.x;

  const char* Abase = (const char*)(A + (size_t)by * 256 * K);
  const char* Bbase = (const char*)(Bw + (size_t)bx * 256 * K);
  size_t rowbytes = (size_t)K * 2;
  int colsw = (li ^ l8) << 4;
  int nkt = K >> 6;

  f32x4 z4 = {0.f, 0.f, 0.f, 0.f};
  f32x4 acc[8][4];
#pragma unroll
  for (int m = 0; m < 8; ++m)
#pragma unroll
    for (int n = 0; n < 4; ++n) acc[m][n] = z4;

#define SG_A(buf, t, r0)                                                      \
  gload_lds16(Abase + (size_t)((r0) + w * 8 + l8) * rowbytes + ((t) << 7) +   \
                  colsw,                                                      \
              (char*)As[buf] + ((r0) + w * 8) * 128)
#define SG_B(buf, t, r0)                                                      \
  gload_lds16(Bbase + (size_t)((r0) + w * 8 + l8) * rowbytes + ((t) << 7) +   \
                  colsw,                                                      \
              (char*)Bs[buf] + ((r0) + w * 8) * 128)

  SG_A(0, 0, 0); SG_A(0, 0, 64); SG_A(0, 0, 128); SG_A(0, 0, 192);
  SG_B(0, 0, 0); SG_B(0, 0, 64); SG_B(0, 0, 128); SG_B(0, 0, 192);
  SG_A(1, 1, 0); SG_A(1, 1, 128); SG_B(1, 1, 0); SG_B(1, 1, 64);
  SG_A(1, 1, 64); SG_A(1, 1, 192);
  asm volatile("s_waitcnt vmcnt(6)" ::: "memory");
  __builtin_amdgcn_s_barrier();
  __builtin_amdgcn_sched_barrier(0);

  int buf = 0;
  bf16x8 af[4][2], bfr[4][2];

#define LDA(mh)                                                               \
  _Pragma("unroll") for (int m = 0; m < 4; ++m) {                             \
    int row = wr * 128 + (mh) * 64 + m * 16 + r16;                            \
    int sw = (row & 7) << 4;                                                  \
    _Pragma("unroll") for (int kk = 0; kk < 2; ++kk)                          \
        af[m][kk] = *(const bf16x8*)(ab + row * 128 +                         \
                                     (((kk << 6) | (hi << 4)) ^ sw));         \
  }
#define LDB(nh)                                                               \
  _Pragma("unroll") for (int n = 0; n < 2; ++n) {                             \
    int row = wc * 64 + (nh) * 32 + n * 16 + r16;                             \
    int sw = (row & 7) << 4;                                                  \
    _Pragma("unroll") for (int kk = 0; kk < 2; ++kk)                          \
        bfr[(nh) * 2 + n][kk] = *(const bf16x8*)(ab2 + row * 128 +            \
                                     (((kk << 6) | (hi << 4)) ^ sw));         \
  }
#define MM(mh, nh)                                                            \
  __builtin_amdgcn_s_setprio(1);                                              \
  _Pragma("unroll") for (int kk = 0; kk < 2; ++kk)                            \
      _Pragma("unroll") for (int m = 0; m < 4; ++m)                           \
          _Pragma("unroll") for (int n = 0; n < 2; ++n)                       \
              acc[(mh) * 4 + m][(nh) * 2 + n] =                               \
      MFMA16(af[m][kk], bfr[(nh) * 2 + n][kk], acc[(mh) * 4 + m][(nh) * 2 + n]); \
  __builtin_amdgcn_s_setprio(0)

#define BAR1                                                                  \
  __builtin_amdgcn_s_barrier();                                               \
  __builtin_amdgcn_sched_barrier(0)
#define BAR2                                                                  \
  __builtin_amdgcn_sched_barrier(0);                                          \
  __builtin_amdgcn_s_barrier();                                               \
  __builtin_amdgcn_sched_barrier(0)

  for (int t = 0; t < nkt; ++t) {
    const char* ab = (const char*)As[buf];
    const char* ab2 = (const char*)Bs[buf];
    bool s1 = (t + 1 < nkt), s2 = (t + 2 < nkt);
    // ---- q0
    LDA(0);
    LDB(0);
    if (s1) { SG_B(buf ^ 1, t + 1, 128); SG_B(buf ^ 1, t + 1, 192); }
    BAR1;
    MM(0, 0);
    BAR2;
    // ---- q1
    LDB(1);
    if (s2) { SG_A(buf, t + 2, 0); SG_A(buf, t + 2, 128); }
    BAR1;
    MM(0, 1);
    BAR2;
    // ---- q2
    LDA(1);
    if (s2) { SG_B(buf, t + 2, 0); SG_B(buf, t + 2, 64); }
    BAR1;
    MM(1, 0);
    BAR2;
    // ---- q3
    if (s2) { SG_A(buf, t + 2, 64); SG_A(buf, t + 2, 192); }
    BAR1;
    MM(1, 1);
    __builtin_amdgcn_sched_barrier(0);
    if (s2) {
      asm volatile("s_waitcnt vmcnt(6)" ::: "memory");
    } else {
      asm volatile("s_waitcnt vmcnt(0)" ::: "memory");
    }
    __builtin_amdgcn_s_barrier();
    __builtin_amdgcn_sched_barrier(0);
    buf ^= 1;
  }
#undef SG_A
#undef SG_B
#undef LDA
#undef LDB
#undef MM
#undef BAR1
#undef BAR2

#pragma unroll
  for (int m = 0; m < 8; ++m)
#pragma unroll
    for (int n = 0; n < 4; ++n) {
      int row0 = by * 256 + wr * 128 + m * 16 + hi * 4;
      int col = bx * 256 + wc * 64 + n * 16 + r16;
      if (MODE == 2) {
        int jt = col >> 10;
        int h = (col >> 6) & 15, dh = col & 63;
        int bb = row0 >> 12, nt0 = row0 & 4095;
        float bcol = bias[col];
        if (jt == 2) {
          ushort4 o;
          o.x = f2bfu(acc[m][n][0] + bcol);
          o.y = f2bfu(acc[m][n][1] + bcol);
          o.z = f2bfu(acc[m][n][2] + bcol);
          o.w = f2bfu(acc[m][n][3] + bcol);
          *(ushort4*)&Vo[(((size_t)bb * 16 + h) * 64 + dh) * 4096 + nt0] = o;
        } else {
          u16* dst = (jt == 0) ? Qo : Ko;
#pragma unroll
          for (int r = 0; r < 4; ++r)
            dst[(((size_t)bb * 16 + h) * 4096 + nt0 + r) * 64 + dh] =
                f2bfu(acc[m][n][r] + bcol);
        }
      } else {
        float bcol = bias[col];
#pragma unroll
        for (int r = 0; r < 4; ++r) {
          int row = row0 + r;
          Cf[(size_t)row * N + col] = acc[m][n][r] + bcol;
        }
      }
    }

  // ---- fused landmark pooling (MODE 2, Q/K tiles only; jt uniform per block)
  if (MODE == 2) {
    int jt = bx >> 2;  // grid x: 0-3 Q, 4-7 K, 8-11 V
    if (jt < 2) {
      float* fo = (jt == 0) ? qlmf : klmf;
      u16* bo = (jt == 0) ? qlmb : klmb;
      int bb = by >> 4;
      int segb = (by * 4) & 63;  // first segment of this by-tile within batch
#pragma unroll
      for (int mh = 0; mh < 2; ++mh) {
        int seg = segb + wr * 2 + mh;
#pragma unroll
        for (int n = 0; n < 4; ++n) {
          int col = bx * 256 + wc * 64 + n * 16 + r16;
          float s = 0.f;
#pragma unroll
          for (int m = 0; m < 4; ++m)
#pragma unroll
            for (int r = 0; r < 4; ++r) s += acc[mh * 4 + m][n][r];
          s += 16.0f * bias[col];
          s += __shfl_xor(s, 16);
          s += __shfl_xor(s, 32);
          if (hi == 0) {
            int h = (col >> 6) & 15, dh = col & 63;
            float val = s * (0.25f / 64.0f);  // mean * SCALE
            size_t o = (((size_t)bb * 16 + h) * 64 + seg) * 64 + dh;
            fo[o] = val;
            bo[o] = f2bfu(val);
          }
        }
      }
    }
  }
}

// -------- attn3 (blocks x<2, 2 chunks x 4 key-batches) || W2 split-K (x>=2)
__global__ __launch_bounds__(256) void attn3_pv_kernel(
    const u16* __restrict__ qlmb, const u16* __restrict__ Kmat,
    const u16* __restrict__ Vt, float* __restrict__ Upart,
    float* __restrict__ rspart,
    const u16* __restrict__ Aw2, const u16* __restrict__ Bw2,
    float* __restrict__ Cp) {
  __shared__ __attribute__((aligned(16))) u16 Elds[4][8192];
  int tid = threadIdx.x, lane = tid & 63, w = tid >> 6;
  int r16 = lane & 15, hi = lane >> 4;
  int l8 = lane >> 3, li = lane & 7;

  if (blockIdx.x >= 2) {
    // ---------------- W2 = P @ G split-K (1024^3), f32 partials
    int wid = (blockIdx.x - 2) * 64 + blockIdx.y;  // [0,256)
    u16* As = &Elds[0][0];
    u16* Bs = &Elds[1][0];
    int wr = w >> 1, wc = w & 1;
    int kz = wid >> 6, bxw = wid & 7, byw = (wid >> 3) & 7;
    const char* Abase = (const char*)(Aw2 + (size_t)byw * 131072 + kz * 256);
    const char* Bbase = (const char*)(Bw2 + (size_t)bxw * 131072 + kz * 256);
    int colsw = (li ^ l8) << 4;
    f32x4 z4 = {0.f, 0.f, 0.f, 0.f};
    f32x4 acc[4][4];
#pragma unroll
    for (int m = 0; m < 4; ++m)
#pragma unroll
      for (int n = 0; n < 4; ++n) acc[m][n] = z4;
    for (int kt = 0; kt < 4; ++kt) {
      int kb = kt << 7;
#pragma unroll
      for (int i = 0; i < 4; ++i) {
        int c = w * 4 + i;
        int rr = c * 8 + l8;
        gload_lds16(Abase + (size_t)rr * 2048 + kb + colsw, (char*)As + c * 1024);
        gload_lds16(Bbase + (size_t)rr * 2048 + kb + colsw, (char*)Bs + c * 1024);
      }
      __syncthreads();
      int sw = (lane & 7) << 4;
#pragma unroll
      for (int kk = 0; kk < 2; ++kk) {
        int kby = (kk << 6) + (hi << 4);
        bf16x8 af[4], bfr[4];
#pragma unroll
        for (int m = 0; m < 4; ++m) {
          int row = wr * 64 + m * 16 + r16;
          af[m] = *(const bf16x8*)((const char*)As + row * 128 + (kby ^ sw));
        }
#pragma unroll
        for (int n = 0; n < 4; ++n) {
          int row = wc * 64 + n * 16 + r16;
          bfr[n] = *(const bf16x8*)((const char*)Bs + row * 128 + (kby ^ sw));
        }
#pragma unroll
        for (int m = 0; m < 4; ++m)
#pragma unroll
          for (int n = 0; n < 4; ++n) acc[m][n] = MFMA16(af[m], bfr[n], acc[m][n]);
      }
      __syncthreads();
    }
#pragma unroll
    for (int m = 0; m < 4; ++m)
#pragma unroll
      for (int n = 0; n < 4; ++n)
#pragma unroll
        for (int r = 0; r < 4; ++r) {
          int row = byw * 128 + wr * 64 + m * 16 + hi * 4 + r;
          int col = bxw * 128 + wc * 64 + n * 16 + r16;
          Cp[(size_t)kz * 1048576 + (size_t)row * 1024 + col] = acc[m][n][r];
        }
    return;
  }

  // ---------------- attn3: scores + exp + (E @ V^T) partials; 4 key-batches
  int chunk = blockIdx.x, bh = blockIdx.y;
  const u16* vtb = Vt + (size_t)bh * 262144;  // V^T: [64][4096] per bh
  const u16* qb = qlmb + (size_t)bh * 4096;
  u16* eb = &Elds[w][0];
  f32x4 z4 = {0.f, 0.f, 0.f, 0.f};

  bf16x8 afr[4][2];
#pragma unroll
  for (int m = 0; m < 4; ++m)
#pragma unroll
    for (int kk = 0; kk < 2; ++kk)
      afr[m][kk] = *(const bf16x8*)(qb + (m * 16 + r16) * 64 + kk * 32 + hi * 8);

  float rs[4][4] = {};
  f32x4 U[4][4];
#pragma unroll
  for (int m = 0; m < 4; ++m)
#pragma unroll
    for (int df = 0; df < 4; ++df) U[m][df] = z4;

  for (int bat = 0; bat < 4; ++bat) {
    int keybase = chunk * 2048 + bat * 512 + w * 128;
    const u16* kb = Kmat + ((size_t)bh * 4096 + keybase) * 64;
    for (int cf = 0; cf < 8; ++cf) {
      f32x4 S[4] = {z4, z4, z4, z4};
#pragma unroll
      for (int kk = 0; kk < 2; ++kk) {
        bf16x8 bfr = *(const bf16x8*)(kb + (size_t)(cf * 16 + r16) * 64 + kk * 32 + hi * 8);
#pragma unroll
        for (int m = 0; m < 4; ++m) S[m] = MFMA16(afr[m][kk], bfr, S[m]);
      }
#pragma unroll
      for (int m = 0; m < 4; ++m)
#pragma unroll
        for (int r = 0; r < 4; ++r) {
          float e = __expf(S[m][r]);  // max-free: logits O(0.1) by construction
          rs[m][r] += e;
          int row = m * 16 + hi * 4 + r;
          int key = cf * 16 + r16;
          *(u16*)((char*)eb + row * 256 + ((key * 2) ^ ((row & 7) << 4))) = f2bfu(e);
        }
    }
    __syncthreads();
    for (int ks = 0; ks < 4; ++ks) {
      bf16x8 ea[4];
#pragma unroll
      for (int m = 0; m < 4; ++m) {
        int row = m * 16 + r16;
        ea[m] = *(const bf16x8*)((char*)eb + row * 256 + (((ks * 32 + hi * 8) * 2) ^ ((row & 7) << 4)));
      }
#pragma unroll
      for (int df = 0; df < 4; ++df) {
        bf16x8 vb8 = *(const bf16x8*)(vtb + (size_t)(df * 16 + r16) * 4096 +
                                      keybase + ks * 32 + hi * 8);
#pragma unroll
        for (int m = 0; m < 4; ++m) U[m][df] = MFMA16(ea[m], vb8, U[m][df]);
      }
    }
    __syncthreads();
  }

#pragma unroll
  for (int m = 0; m < 4; ++m)
#pragma unroll
    for (int r = 0; r < 4; ++r) {
      float v = rs[m][r];
      v += __shfl_xor(v, 1); v += __shfl_xor(v, 2);
      v += __shfl_xor(v, 4); v += __shfl_xor(v, 8);
      rs[m][r] = v;
    }
  if (r16 == 0) {
    float* rp = rspart + (((size_t)bh * 2 + chunk) * 4 + w) * 64;
#pragma unroll
    for (int m = 0; m < 4; ++m)
#pragma unroll
      for (int r = 0; r < 4; ++r) rp[m * 16 + hi * 4 + r] = rs[m][r];
  }
  float* up = Upart + (((size_t)bh * 2 + chunk) * 4 + w) * 4096;
#pragma unroll
  for (int m = 0; m < 4; ++m)
#pragma unroll
    for (int df = 0; df < 4; ++df)
#pragma unroll
      for (int r = 0; r < 4; ++r)
        up[(m * 16 + hi * 4 + r) * 64 + df * 16 + r16] = U[m][df][r];
}

// ------------- combine (blocks 0..63, 512 thr): inline T-reduce + attn2
// softmax + NS + W = A2inv @ T; blocks 64..575: w2_reduce (Cp -> W2 bf16).
__device__ __forceinline__ void mm64d(const float (*AT)[68], const float (*Bm)[68],
                                      float (*C)[68], float (*CT)[68],
                                      float alpha, float dconst, bool dmode,
                                      int tid) {
  int tr = (tid >> 4) << 1;
  int tc = (tid & 15) << 2;
  float acc[2][4] = {};
#pragma unroll 4
  for (int k = 0; k < 64; ++k) {
    float2 av = *(const float2*)&AT[k][tr];
    float4 bv = *(const float4*)&Bm[k][tc];
    float aa[2] = {av.x, av.y};
    float bb[4] = {bv.x, bv.y, bv.z, bv.w};
#pragma unroll
    for (int i = 0; i < 2; ++i)
#pragma unroll
      for (int j = 0; j < 4; ++j) acc[i][j] = fmaf(aa[i], bb[j], acc[i][j]);
  }
#pragma unroll
  for (int i = 0; i < 2; ++i)
#pragma unroll
    for (int j = 0; j < 4; ++j) {
      float vv = acc[i][j] * alpha;
      if (CT) CT[tc + j][tr + i] = vv;
      C[tr + i][tc + j] =
          dmode ? (((tr + i) == (tc + j)) ? dconst - vv : -vv) : vv;
    }
}

__global__ __launch_bounds__(512) void combine_ns_kernel(
    const float* __restrict__ Upart, const float* __restrict__ rspart,
    const float* __restrict__ qlmf, const float* __restrict__ klmf,
    u16* __restrict__ WT, const float* __restrict__ Cp,
    u16* __restrict__ W2b) {
  int tid = threadIdx.x;
  if (blockIdx.x >= 64) {  // ---- w2_reduce: 512 blocks x 512 threads
    int idx4 = (blockIdx.x - 64) * 512 + tid;
    const float4* p = (const float4*)Cp + idx4;
    float4 s = p[0];
    float4 b = p[262144], c = p[524288], d = p[786432];
    s.x += b.x + c.x + d.x;
    s.y += b.y + c.y + d.y;
    s.z += b.z + c.z + d.z;
    s.w += b.w + c.w + d.w;
    ushort4 o;
    o.x = f2bfu(s.x); o.y = f2bfu(s.y); o.z = f2bfu(s.z); o.w = f2bfu(s.w);
    ((ushort4*)W2b)[idx4] = o;
    return;
  }
  __shared__ __attribute__((aligned(16))) float A2T[64][68];
  __shared__ __attribute__((aligned(16))) float Vv[64][68];
  __shared__ __attribute__((aligned(16))) float VT[64][68];
  __shared__ __attribute__((aligned(16))) float KV[64][68];
  __shared__ __attribute__((aligned(16))) float KVT[64][68];
  __shared__ __attribute__((aligned(16))) float T2[64][68];
  __shared__ __attribute__((aligned(16))) float T4[64][68];
  __shared__ __attribute__((aligned(16))) float Tm[64][68];
  __shared__ float rsum[64], redbuf[64];
  __shared__ float scal;
  int bh = blockIdx.x;

  // Inline reduce_t: rsum then Tm = (sum of 8 U-partials)/rsum.
  if (tid < 64) {
    float s = 0.f;
    const float* rp = rspart + (size_t)bh * 512 + tid;
#pragma unroll 8
    for (int p = 0; p < 8; ++p) s += rp[p * 64];
    rsum[tid] = s;
  }
  __syncthreads();
  for (int idx4 = tid; idx4 < 1024; idx4 += 512) {
    const float4* up = (const float4*)(Upart + (size_t)bh * 32768) + idx4;
    float4 s = {0.f, 0.f, 0.f, 0.f};
#pragma unroll 8
    for (int p = 0; p < 8; ++p) {
      float4 v = up[p * 1024];
      s.x += v.x; s.y += v.y; s.z += v.z; s.w += v.w;
    }
    float inv = 1.0f / rsum[idx4 >> 4];
    int r = idx4 >> 4, c0 = (idx4 & 15) << 2;
    Tm[r][c0] = s.x * inv; Tm[r][c0 + 1] = s.y * inv;
    Tm[r][c0 + 2] = s.z * inv; Tm[r][c0 + 3] = s.w * inv;
  }
  for (int idx = tid; idx < 4096; idx += 512) {
    int r = idx >> 6, c = idx & 63;
    Vv[c][r] = qlmf[(size_t)bh * 4096 + idx];  // qlm^T
    VT[c][r] = klmf[(size_t)bh * 4096 + idx];  // klm^T
  }
  __syncthreads();
  mm64d(&Vv[0], &VT[0], &T2[0], nullptr, 1.0f, 0.f, false, tid);  // S2
  __syncthreads();
  // Parallel softmax: row = tid>>3, 8 lanes per row each covering 8 cols.
  {
    int row = tid >> 3, sub = tid & 7, cb = sub * 8;
    float mx = -1e30f;
#pragma unroll
    for (int j = 0; j < 8; ++j) mx = fmaxf(mx, T2[row][cb + j]);
    mx = fmaxf(mx, __shfl_xor(mx, 1));
    mx = fmaxf(mx, __shfl_xor(mx, 2));
    mx = fmaxf(mx, __shfl_xor(mx, 4));
    float e[8];
    float s = 0.f;
#pragma unroll
    for (int j = 0; j < 8; ++j) { e[j] = __expf(T2[row][cb + j] - mx); s += e[j]; }
    s += __shfl_xor(s, 1); s += __shfl_xor(s, 2); s += __shfl_xor(s, 4);
    float inv = 1.f / s;
#pragma unroll
    for (int j = 0; j < 8; ++j) {
      float p = e[j] * inv;
      T2[row][cb + j] = p;
      A2T[cb + j][row] = p;
    }
  }
  __syncthreads();
  // V0 = max colsum (softmax entries positive); VI = max rowsum = 1 exactly.
  {
    int col = tid >> 3, sub = tid & 7;
    float cs = 0.f;
#pragma unroll
    for (int j = 0; j < 8; ++j) cs += T2[sub * 8 + j][col];
    cs += __shfl_xor(cs, 1); cs += __shfl_xor(cs, 2); cs += __shfl_xor(cs, 4);
    if (sub == 0) redbuf[col] = cs;
  }
  __syncthreads();
  if (tid < 64) {
    float v0 = redbuf[tid];
#pragma unroll
    for (int m = 1; m < 64; m <<= 1) v0 = fmaxf(v0, __shfl_xor(v0, m));
    if (tid == 0) scal = 1.0f / v0;
  }
  __syncthreads();
  for (int idx = tid; idx < 4096; idx += 512) {
    int r = idx >> 6, c = idx & 63;
    Vv[r][c] = A2T[r][c] * scal;  // V0 = A2^T / (V0*VI), VI == 1
    VT[r][c] = T2[r][c] * scal;   // V0^T
  }
  __syncthreads();
  float (*Vt_r)[68] = VT;
  float (*Vt_w)[68] = KV;
#pragma unroll 1
  for (int it = 0; it < 6; ++it) {
    mm64d(&A2T[0], &Vv[0], &T2[0], &KVT[0], 1.0f, 7.0f, true, tid);
    __syncthreads();
    mm64d(&KVT[0], &T2[0], &T4[0], nullptr, 1.0f, 15.0f, true, tid);
    __syncthreads();
    mm64d(&KVT[0], &T4[0], &T2[0], nullptr, 1.0f, 13.0f, true, tid);
    __syncthreads();
    mm64d(Vt_r, &T2[0], &Vv[0], Vt_w, 0.25f, 0.f, false, tid);
    __syncthreads();
    float (*tmp)[68] = Vt_r; Vt_r = Vt_w; Vt_w = tmp;
  }
  mm64d(Vt_r, &Tm[0], &T2[0], nullptr, 1.0f, 0.f, false, tid);  // W = A2inv @ T
  __syncthreads();
  for (int idx = tid; idx < 4096; idx += 512) {
    int r = idx >> 6, c = idx & 63;
    WT[(size_t)bh * 4096 + c * 64 + r] = f2bfu(T2[r][c]);  // store W^T bf16
  }
}

// ------------------- final: softmax(q @ klm^T) @ W  ->  attn_out (B,N,C) bf16
__global__ __launch_bounds__(256) void attn1_out_kernel(
    const u16* __restrict__ Q, const u16* __restrict__ klmb,
    const u16* __restrict__ WT, u16* __restrict__ AO) {
  __shared__ __attribute__((aligned(16))) u16 Elds[4][2048];  // per-wave 32x64 bf16
  int bh = blockIdx.y;
  int b = bh >> 4, h = bh & 15;
  int tid = threadIdx.x, lane = tid & 63, w = tid >> 6;
  int r16 = lane & 15, hi = lane >> 4;
  int rowbase = blockIdx.x * 128 + w * 32;
  const u16* qb = Q + ((size_t)bh * 4096 + rowbase) * 64;
  const u16* kb = klmb + (size_t)bh * 4096;
  const u16* wtb = WT + (size_t)bh * 4096;
  u16* eb = &Elds[w][0];
  f32x4 z4 = {0.f, 0.f, 0.f, 0.f};

  bf16x8 afr[2][2];
#pragma unroll
  for (int mi = 0; mi < 2; ++mi)
#pragma unroll
    for (int kk = 0; kk < 2; ++kk)
      afr[mi][kk] = *(const bf16x8*)(qb + (mi * 16 + r16) * 64 + kk * 32 + hi * 8);

  float rs[2][4] = {};
  for (int cf = 0; cf < 4; ++cf) {
    f32x4 S[2] = {z4, z4};
#pragma unroll
    for (int kk = 0; kk < 2; ++kk) {
      bf16x8 bfr = *(const bf16x8*)(kb + (cf * 16 + r16) * 64 + kk * 32 + hi * 8);
#pragma unroll
      for (int mi = 0; mi < 2; ++mi) S[mi] = MFMA16(afr[mi][kk], bfr, S[mi]);
    }
#pragma unroll
    for (int mi = 0; mi < 2; ++mi)
#pragma unroll
      for (int r = 0; r < 4; ++r) {
        float e = __expf(S[mi][r]);
        rs[mi][r] += e;
        int row = mi * 16 + hi * 4 + r;
        int key = cf * 16 + r16;
        *(u16*)((char*)eb + row * 128 + ((key * 2) ^ ((row & 7) << 4))) = f2bfu(e);
      }
  }
#pragma unroll
  for (int mi = 0; mi < 2; ++mi)
#pragma unroll
    for (int r = 0; r < 4; ++r) {
      float v = rs[mi][r];
      v += __shfl_xor(v, 1); v += __shfl_xor(v, 2);
      v += __shfl_xor(v, 4); v += __shfl_xor(v, 8);
      rs[mi][r] = v;
    }
  __syncthreads();

  f32x4 O[2][4];
#pragma unroll
  for (int mi = 0; mi < 2; ++mi)
#pragma unroll
    for (int df = 0; df < 4; ++df) O[mi][df] = z4;
  for (int ks = 0; ks < 2; ++ks) {
    bf16x8 ea[2];
#pragma unroll
    for (int mi = 0; mi < 2; ++mi) {
      int row = mi * 16 + r16;
      ea[mi] = *(const bf16x8*)((char*)eb + row * 128 + (((ks * 32 + hi * 8) * 2) ^ ((row & 7) << 4)));
    }
#pragma unroll
    for (int df = 0; df < 4; ++df) {
      bf16x8 wfr = *(const bf16x8*)(wtb + (df * 16 + r16) * 64 + ks * 32 + hi * 8);
#pragma unroll
      for (int mi = 0; mi < 2; ++mi) O[mi][df] = MFMA16(ea[mi], wfr, O[mi][df]);
    }
  }
#pragma unroll
  for (int mi = 0; mi < 2; ++mi)
#pragma unroll
    for (int df = 0; df < 4; ++df)
#pragma unroll
      for (int r = 0; r < 4; ++r) {
        int row = mi * 16 + hi * 4 + r;
        int n = rowbase + row;
        int col = h * 64 + df * 16 + r16;
        float val = O[mi][df][r] / rs[mi][r];
        AO[((size_t)b * 4096 + n) * 1024 + col] = f2bfu(val);
      }
}

// ---------------------------------------------------------------- launcher
extern "C" void kernel_launch(void* const* d_in, const int* in_sizes, int n_in,
                              void* d_out, int out_size, void* d_ws, size_t ws_size,
                              hipStream_t stream) {
  (void)in_sizes; (void)n_in; (void)out_size; (void)ws_size;
  const float* x       = (const float*)d_in[0];
  const float* ln_w    = (const float*)d_in[1];
  const float* ln_b    = (const float*)d_in[2];
  const float* qkv_w   = (const float*)d_in[3];
  const float* qkv_b   = (const float*)d_in[4];
  const float* gamma_w = (const float*)d_in[5];
  const float* gamma_b = (const float*)d_in[6];
  const float* proj_w  = (const float*)d_in[7];
  const float* proj_b  = (const float*)d_in[8];

  char* ws = (char*)d_ws;
  u16* XN     = (u16*)(ws + 0);           // xn; UP[0,16M)+CPF[16.7M,33.5M); AO
  u16* Qb     = (u16*)(ws + 33554432);
  u16* Kb     = (u16*)(ws + 67108864);    // K (dead after attn3)
  u16* Vb     = (u16*)(ws + 100663296);   // V^T; W2b overlay after attn3
  u16* QKVW   = (u16*)(ws + 134217728);
  u16* GTb    = (u16*)(ws + 140509184);   // gamma^T bf16
  u16* PW     = (u16*)(ws + 142606336);
  float* QLMF = (float*)(ws + 144703488);
  float* KLMF = (float*)(ws + 145752064);
  u16* QLMB   = (u16*)(ws + 146800640);
  u16* KLMB   = (u16*)(ws + 147324928);
  float* RSP  = (float*)(ws + 147849216); // 128KB used
  float* B2F  = (float*)(ws + 148111360); // 4KB (RSP region upper half)
  u16* WTb    = (u16*)(ws + 148373504);
  float* UP   = (float*)XN;               // xn dead after qkv GEMM
  float* CPF  = (float*)(ws + 16777216);  // written attn3-launch (xn dead)
  u16* W2b    = (u16*)(ws + 102760448);   // on Vb (dead after attn3)

  prep_kernel<<<17920, 256, 0, stream>>>(x, ln_w, ln_b, XN, qkv_w, QKVW);
  gemm_bt<2><<<dim3(12, 64, 2), 512, 0, stream>>>(
      XN, QKVW, qkv_b, nullptr, nullptr, Qb, Kb, Vb,
      QLMF, QLMB, KLMF, KLMB,
      proj_w, PW, gamma_w, GTb, gamma_b, proj_b, B2F,
      16384, 3072, 1024);
  attn3_pv_kernel<<<dim3(6, 64), 256, 0, stream>>>(QLMB, Kb, Vb, UP, RSP,
                                                   PW, GTb, CPF);
  combine_ns_kernel<<<576, 512, 0, stream>>>(UP, RSP, QLMF, KLMF, WTb, CPF, W2b);
  attn1_out_kernel<<<dim3(32, 64), 256, 0, stream>>>(Qb, KLMB, WTb, XN);
  gemm_bt<1><<<dim3(4, 64), 512, 0, stream>>>(
      XN, W2b, B2F, (float*)d_out, nullptr, nullptr, nullptr, nullptr,
      nullptr, nullptr, nullptr, nullptr,
      nullptr, nullptr, nullptr, nullptr, nullptr, nullptr, nullptr,
      16384, 1024, 1024);
}

// Round 13
// 349.638 us; speedup vs baseline: 1.0771x; 1.0771x over previous
//
#include <hip/hip_runtime.h>
#include <stdint.h>

typedef unsigned short u16;
typedef short bf16x8 __attribute__((ext_vector_type(8)));
typedef float f32x4 __attribute__((ext_vector_type(4)));

#define MFMA16(a, b, c) __builtin_amdgcn_mfma_f32_16x16x32_bf16((a), (b), (c), 0, 0, 0)

static __device__ __forceinline__ float bfu2f(u16 u) {
  union { unsigned int i; float f; } z; z.i = ((unsigned int)u) << 16; return z.f;
}
static __device__ __forceinline__ u16 f2bfu(float f) {
  union { float f; unsigned int i; } z; z.f = f;
  unsigned int i = z.i;
  return (u16)((i + 0x7fffu + ((i >> 16) & 1u)) >> 16);
}

__device__ __forceinline__ void gload_lds16(const void* g, void* l) {
  __builtin_amdgcn_global_load_lds((const __attribute__((address_space(1))) void*)g,
                                   (__attribute__((address_space(3))) void*)l, 16, 0, 0);
}

// ---------------- prep: LayerNorm || weight-cvt || gamma-transpose || bias2
// blocks [0,16384): ln; [16384,18432): cvt; [18432,18688): G^T; [18688,18692): b2.
__global__ __launch_bounds__(256) void prep_kernel(
    const float* __restrict__ x, const float* __restrict__ lw,
    const float* __restrict__ lb, u16* __restrict__ xn,
    const float* __restrict__ qkvw, u16* __restrict__ QKVW,
    const float* __restrict__ projw, u16* __restrict__ PW,
    const float* __restrict__ G, u16* __restrict__ GT,
    const float* __restrict__ gb, const float* __restrict__ pb,
    float* __restrict__ b2) {
  int blk = blockIdx.x;
  int t = threadIdx.x;
  if (blk < 16384) {  // ---- LayerNorm
    int row = blk;
    const float4* xr = (const float4*)(x + (size_t)row * 1024);
    float4 v = xr[t];
    float s = v.x + v.y + v.z + v.w;
    float ss = v.x * v.x + v.y * v.y + v.z * v.z + v.w * v.w;
#pragma unroll
    for (int m = 1; m < 64; m <<= 1) { s += __shfl_xor(s, m); ss += __shfl_xor(ss, m); }
    __shared__ float sb[4], ssb[4];
    int lane = t & 63, wvi = t >> 6;
    if (lane == 0) { sb[wvi] = s; ssb[wvi] = ss; }
    __syncthreads();
    s = sb[0] + sb[1] + sb[2] + sb[3];
    ss = ssb[0] + ssb[1] + ssb[2] + ssb[3];
    float mu = s * (1.0f / 1024.0f);
    float var = ss * (1.0f / 1024.0f) - mu * mu;
    float rstd = rsqrtf(var + 1e-5f);
    float4 wv4 = ((const float4*)lw)[t];
    float4 bv4 = ((const float4*)lb)[t];
    ushort4 o;
    o.x = f2bfu((v.x - mu) * rstd * wv4.x + bv4.x);
    o.y = f2bfu((v.y - mu) * rstd * wv4.y + bv4.y);
    o.z = f2bfu((v.z - mu) * rstd * wv4.z + bv4.z);
    o.w = f2bfu((v.w - mu) * rstd * wv4.w + bv4.w);
    ((ushort4*)xn)[(size_t)row * 256 + t] = o;
  } else if (blk < 18432) {  // ---- f32->bf16 cvt (qkv_w + proj_w)
    int idx = (blk - 16384) * 256 + t;
    for (int i = idx; i < 1048576; i += 524288) {
      int j = i << 2;
      const float* s2; u16* d; int off;
      if (j < 3145728) { s2 = qkvw; d = QKVW; off = j; }
      else             { s2 = projw; d = PW; off = j - 3145728; }
      float4 v = *(const float4*)(s2 + off);
      ushort4 o;
      o.x = f2bfu(v.x); o.y = f2bfu(v.y); o.z = f2bfu(v.z); o.w = f2bfu(v.w);
      *(ushort4*)(d + off) = o;
    }
  } else if (blk < 18688) {  // ---- transpose gamma_w -> GT bf16
    __shared__ float tt[64][65];
    int tg = blk - 18432;
    int tr = (tg >> 4) * 64, tc = (tg & 15) * 64;
    int l = t & 63, y = t >> 6;
    for (int r = y; r < 64; r += 4)
      tt[r][l] = G[(size_t)(tr + r) * 1024 + tc + l];
    __syncthreads();
    for (int rr = y; rr < 64; rr += 4)
      GT[(size_t)(tc + rr) * 1024 + tr + l] = f2bfu(tt[l][rr]);
  } else {  // ---- b2 = proj_w @ gamma_b + proj_b
    int i = (blk - 18688) * 256 + t;
    const float4* pr = (const float4*)(projw + (size_t)i * 1024);
    const float4* g4 = (const float4*)gb;
    float s = 0.f;
    for (int k = 0; k < 256; ++k) {
      float4 a = pr[k], b = g4[k];
      s += a.x * b.x + a.y * b.y + a.z * b.z + a.w * b.w;
    }
    b2[i] = s + pb[i];
  }
}

// --------------------------------------------------- GEMM  C = A @ Bw^T + bias
// m201-style 8-phase schedule (round-7/11 verified-best form): BM=BN=256, BK=64,
// 8 waves (2Mx4N), double-buffered LDS, counted vmcnt(6) once per K-tile.
// Bijective XCD swizzle. MODE 1: f32 out; MODE 2: qkv scatter (V transposed)
// + fused landmark pooling.
template <int MODE>
__global__ __launch_bounds__(512, 2) void gemm_bt(
    const u16* __restrict__ A, const u16* __restrict__ Bw,
    const float* __restrict__ bias,
    float* __restrict__ Cf, u16* __restrict__ Cb,
    u16* __restrict__ Qo, u16* __restrict__ Ko, u16* __restrict__ Vo,
    float* __restrict__ qlmf, u16* __restrict__ qlmb,
    float* __restrict__ klmf, u16* __restrict__ klmb,
    int M, int N, int K) {
  __shared__ __attribute__((aligned(16))) u16 As[2][16384];  // [256][64] bf16
  __shared__ __attribute__((aligned(16))) u16 Bs[2][16384];  // [256][64] bf16
  int tid = threadIdx.x;
  int lane = tid & 63;
  int w = tid >> 6;            // 0..7
  int wr = w >> 2, wc = w & 3; // wave grid 2 (M) x 4 (N)
  int r16 = lane & 15, hi = lane >> 4;
  int l8 = lane >> 3, li = lane & 7;

  int nwg = gridDim.x * gridDim.y;
  int flat = blockIdx.y * gridDim.x + blockIdx.x;
  int q8 = nwg >> 3;
  int swz = (flat & 7) * q8 + (flat >> 3);
  int bx = swz % gridDim.x, by = swz / gridDim.x;

  const char* Abase = (const char*)(A + (size_t)by * 256 * K);
  const char* Bbase = (const char*)(Bw + (size_t)bx * 256 * K);
  size_t rowbytes = (size_t)K * 2;
  int colsw = (li ^ l8) << 4;
  int nkt = K >> 6;

  f32x4 z4 = {0.f, 0.f, 0.f, 0.f};
  f32x4 acc[8][4];
#pragma unroll
  for (int m = 0; m < 8; ++m)
#pragma unroll
    for (int n = 0; n < 4; ++n) acc[m][n] = z4;

#define SG_A(buf, t, r0)                                                      \
  gload_lds16(Abase + (size_t)((r0) + w * 8 + l8) * rowbytes + ((t) << 7) +   \
                  colsw,                                                      \
              (char*)As[buf] + ((r0) + w * 8) * 128)
#define SG_B(buf, t, r0)                                                      \
  gload_lds16(Bbase + (size_t)((r0) + w * 8 + l8) * rowbytes + ((t) << 7) +   \
                  colsw,                                                      \
              (char*)Bs[buf] + ((r0) + w * 8) * 128)

  SG_A(0, 0, 0); SG_A(0, 0, 64); SG_A(0, 0, 128); SG_A(0, 0, 192);
  SG_B(0, 0, 0); SG_B(0, 0, 64); SG_B(0, 0, 128); SG_B(0, 0, 192);
  SG_A(1, 1, 0); SG_A(1, 1, 128); SG_B(1, 1, 0); SG_B(1, 1, 64);
  SG_A(1, 1, 64); SG_A(1, 1, 192);
  asm volatile("s_waitcnt vmcnt(6)" ::: "memory");
  __builtin_amdgcn_s_barrier();
  __builtin_amdgcn_sched_barrier(0);

  int buf = 0;
  bf16x8 af[4][2], bfr[4][2];

#define LDA(mh)                                                               \
  _Pragma("unroll") for (int m = 0; m < 4; ++m) {                             \
    int row = wr * 128 + (mh) * 64 + m * 16 + r16;                            \
    int sw = (row & 7) << 4;                                                  \
    _Pragma("unroll") for (int kk = 0; kk < 2; ++kk)                          \
        af[m][kk] = *(const bf16x8*)(ab + row * 128 +                         \
                                     (((kk << 6) | (hi << 4)) ^ sw));         \
  }
#define LDB(nh)                                                               \
  _Pragma("unroll") for (int n = 0; n < 2; ++n) {                             \
    int row = wc * 64 + (nh) * 32 + n * 16 + r16;                             \
    int sw = (row & 7) << 4;                                                  \
    _Pragma("unroll") for (int kk = 0; kk < 2; ++kk)                          \
        bfr[(nh) * 2 + n][kk] = *(const bf16x8*)(ab2 + row * 128 +            \
                                     (((kk << 6) | (hi << 4)) ^ sw));         \
  }
#define MM(mh, nh)                                                            \
  __builtin_amdgcn_s_setprio(1);                                              \
  _Pragma("unroll") for (int kk = 0; kk < 2; ++kk)                            \
      _Pragma("unroll") for (int m = 0; m < 4; ++m)                           \
          _Pragma("unroll") for (int n = 0; n < 2; ++n)                       \
              acc[(mh) * 4 + m][(nh) * 2 + n] =                               \
      MFMA16(af[m][kk], bfr[(nh) * 2 + n][kk], acc[(mh) * 4 + m][(nh) * 2 + n]); \
  __builtin_amdgcn_s_setprio(0)

#define BAR1                                                                  \
  __builtin_amdgcn_s_barrier();                                               \
  __builtin_amdgcn_sched_barrier(0)
#define BAR2                                                                  \
  __builtin_amdgcn_sched_barrier(0);                                          \
  __builtin_amdgcn_s_barrier();                                               \
  __builtin_amdgcn_sched_barrier(0)

  for (int t = 0; t < nkt; ++t) {
    const char* ab = (const char*)As[buf];
    const char* ab2 = (const char*)Bs[buf];
    bool s1 = (t + 1 < nkt), s2 = (t + 2 < nkt);
    // ---- q0
    LDA(0);
    LDB(0);
    if (s1) { SG_B(buf ^ 1, t + 1, 128); SG_B(buf ^ 1, t + 1, 192); }
    BAR1;
    MM(0, 0);
    BAR2;
    // ---- q1
    LDB(1);
    if (s2) { SG_A(buf, t + 2, 0); SG_A(buf, t + 2, 128); }
    BAR1;
    MM(0, 1);
    BAR2;
    // ---- q2
    LDA(1);
    if (s2) { SG_B(buf, t + 2, 0); SG_B(buf, t + 2, 64); }
    BAR1;
    MM(1, 0);
    BAR2;
    // ---- q3
    if (s2) { SG_A(buf, t + 2, 64); SG_A(buf, t + 2, 192); }
    BAR1;
    MM(1, 1);
    __builtin_amdgcn_sched_barrier(0);
    if (s2) {
      asm volatile("s_waitcnt vmcnt(6)" ::: "memory");
    } else {
      asm volatile("s_waitcnt vmcnt(0)" ::: "memory");
    }
    __builtin_amdgcn_s_barrier();
    __builtin_amdgcn_sched_barrier(0);
    buf ^= 1;
  }
#undef SG_A
#undef SG_B
#undef LDA
#undef LDB
#undef MM
#undef BAR1
#undef BAR2

#pragma unroll
  for (int m = 0; m < 8; ++m)
#pragma unroll
    for (int n = 0; n < 4; ++n) {
      int row0 = by * 256 + wr * 128 + m * 16 + hi * 4;
      int col = bx * 256 + wc * 64 + n * 16 + r16;
      if (MODE == 2) {
        int jt = col >> 10;
        int h = (col >> 6) & 15, dh = col & 63;
        int bb = row0 >> 12, nt0 = row0 & 4095;
        float bcol = bias[col];
        if (jt == 2) {
          ushort4 o;
          o.x = f2bfu(acc[m][n][0] + bcol);
          o.y = f2bfu(acc[m][n][1] + bcol);
          o.z = f2bfu(acc[m][n][2] + bcol);
          o.w = f2bfu(acc[m][n][3] + bcol);
          *(ushort4*)&Vo[(((size_t)bb * 16 + h) * 64 + dh) * 4096 + nt0] = o;
        } else {
          u16* dst = (jt == 0) ? Qo : Ko;
#pragma unroll
          for (int r = 0; r < 4; ++r)
            dst[(((size_t)bb * 16 + h) * 4096 + nt0 + r) * 64 + dh] =
                f2bfu(acc[m][n][r] + bcol);
        }
      } else {
        float bcol = bias[col];
#pragma unroll
        for (int r = 0; r < 4; ++r) {
          int row = row0 + r;
          Cf[(size_t)row * N + col] = acc[m][n][r] + bcol;
        }
      }
    }

  // ---- fused landmark pooling (MODE 2, Q/K tiles only; jt uniform per block)
  if (MODE == 2) {
    int jt = bx >> 2;  // grid x: 0-3 Q, 4-7 K, 8-11 V
    if (jt < 2) {
      float* fo = (jt == 0) ? qlmf : klmf;
      u16* bo = (jt == 0) ? qlmb : klmb;
      int bb = by >> 4;
      int segb = (by * 4) & 63;  // first segment of this by-tile within batch
#pragma unroll
      for (int mh = 0; mh < 2; ++mh) {
        int seg = segb + wr * 2 + mh;
#pragma unroll
        for (int n = 0; n < 4; ++n) {
          int col = bx * 256 + wc * 64 + n * 16 + r16;
          float s = 0.f;
#pragma unroll
          for (int m = 0; m < 4; ++m)
#pragma unroll
            for (int r = 0; r < 4; ++r) s += acc[mh * 4 + m][n][r];
          s += 16.0f * bias[col];
          s += __shfl_xor(s, 16);
          s += __shfl_xor(s, 32);
          if (hi == 0) {
            int h = (col >> 6) & 15, dh = col & 63;
            float val = s * (0.25f / 64.0f);  // mean * SCALE
            size_t o = (((size_t)bb * 16 + h) * 64 + seg) * 64 + dh;
            fo[o] = val;
            bo[o] = f2bfu(val);
          }
        }
      }
    }
  }
}

// -------- attn3 (blocks x<2, 2 chunks x 4 key-batches) || W2 split-K (x>=2)
__global__ __launch_bounds__(256) void attn3_pv_kernel(
    const u16* __restrict__ qlmb, const u16* __restrict__ Kmat,
    const u16* __restrict__ Vt, float* __restrict__ Upart,
    float* __restrict__ rspart,
    const u16* __restrict__ Aw2, const u16* __restrict__ Bw2,
    float* __restrict__ Cp) {
  __shared__ __attribute__((aligned(16))) u16 Elds[4][8192];
  int tid = threadIdx.x, lane = tid & 63, w = tid >> 6;
  int r16 = lane & 15, hi = lane >> 4;
  int l8 = lane >> 3, li = lane & 7;

  if (blockIdx.x >= 2) {
    // ---------------- W2 = P @ G split-K (1024^3), f32 partials
    int wid = (blockIdx.x - 2) * 64 + blockIdx.y;  // [0,256)
    u16* As = &Elds[0][0];
    u16* Bs = &Elds[1][0];
    int wr = w >> 1, wc = w & 1;
    int kz = wid >> 6, bxw = wid & 7, byw = (wid >> 3) & 7;
    const char* Abase = (const char*)(Aw2 + (size_t)byw * 131072 + kz * 256);
    const char* Bbase = (const char*)(Bw2 + (size_t)bxw * 131072 + kz * 256);
    int colsw = (li ^ l8) << 4;
    f32x4 z4 = {0.f, 0.f, 0.f, 0.f};
    f32x4 acc[4][4];
#pragma unroll
    for (int m = 0; m < 4; ++m)
#pragma unroll
      for (int n = 0; n < 4; ++n) acc[m][n] = z4;
    for (int kt = 0; kt < 4; ++kt) {
      int kb = kt << 7;
#pragma unroll
      for (int i = 0; i < 4; ++i) {
        int c = w * 4 + i;
        int rr = c * 8 + l8;
        gload_lds16(Abase + (size_t)rr * 2048 + kb + colsw, (char*)As + c * 1024);
        gload_lds16(Bbase + (size_t)rr * 2048 + kb + colsw, (char*)Bs + c * 1024);
      }
      __syncthreads();
      int sw = (lane & 7) << 4;
#pragma unroll
      for (int kk = 0; kk < 2; ++kk) {
        int kby = (kk << 6) + (hi << 4);
        bf16x8 af[4], bfr[4];
#pragma unroll
        for (int m = 0; m < 4; ++m) {
          int row = wr * 64 + m * 16 + r16;
          af[m] = *(const bf16x8*)((const char*)As + row * 128 + (kby ^ sw));
        }
#pragma unroll
        for (int n = 0; n < 4; ++n) {
          int row = wc * 64 + n * 16 + r16;
          bfr[n] = *(const bf16x8*)((const char*)Bs + row * 128 + (kby ^ sw));
        }
#pragma unroll
        for (int m = 0; m < 4; ++m)
#pragma unroll
          for (int n = 0; n < 4; ++n) acc[m][n] = MFMA16(af[m], bfr[n], acc[m][n]);
      }
      __syncthreads();
    }
#pragma unroll
    for (int m = 0; m < 4; ++m)
#pragma unroll
      for (int n = 0; n < 4; ++n)
#pragma unroll
        for (int r = 0; r < 4; ++r) {
          int row = byw * 128 + wr * 64 + m * 16 + hi * 4 + r;
          int col = bxw * 128 + wc * 64 + n * 16 + r16;
          Cp[(size_t)kz * 1048576 + (size_t)row * 1024 + col] = acc[m][n][r];
        }
    return;
  }

  // ---------------- attn3: scores + exp + (E @ V^T) partials; 4 key-batches
  int chunk = blockIdx.x, bh = blockIdx.y;
  const u16* vtb = Vt + (size_t)bh * 262144;  // V^T: [64][4096] per bh
  const u16* qb = qlmb + (size_t)bh * 4096;
  u16* eb = &Elds[w][0];
  f32x4 z4 = {0.f, 0.f, 0.f, 0.f};

  bf16x8 afr[4][2];
#pragma unroll
  for (int m = 0; m < 4; ++m)
#pragma unroll
    for (int kk = 0; kk < 2; ++kk)
      afr[m][kk] = *(const bf16x8*)(qb + (m * 16 + r16) * 64 + kk * 32 + hi * 8);

  float rs[4][4] = {};
  f32x4 U[4][4];
#pragma unroll
  for (int m = 0; m < 4; ++m)
#pragma unroll
    for (int df = 0; df < 4; ++df) U[m][df] = z4;

  for (int bat = 0; bat < 4; ++bat) {
    int keybase = chunk * 2048 + bat * 512 + w * 128;
    const u16* kb = Kmat + ((size_t)bh * 4096 + keybase) * 64;
    for (int cf = 0; cf < 8; ++cf) {
      f32x4 S[4] = {z4, z4, z4, z4};
#pragma unroll
      for (int kk = 0; kk < 2; ++kk) {
        bf16x8 bfr = *(const bf16x8*)(kb + (size_t)(cf * 16 + r16) * 64 + kk * 32 + hi * 8);
#pragma unroll
        for (int m = 0; m < 4; ++m) S[m] = MFMA16(afr[m][kk], bfr, S[m]);
      }
#pragma unroll
      for (int m = 0; m < 4; ++m)
#pragma unroll
        for (int r = 0; r < 4; ++r) {
          float e = __expf(S[m][r]);  // max-free: logits O(0.1) by construction
          rs[m][r] += e;
          int row = m * 16 + hi * 4 + r;
          int key = cf * 16 + r16;
          *(u16*)((char*)eb + row * 256 + ((key * 2) ^ ((row & 7) << 4))) = f2bfu(e);
        }
    }
    __syncthreads();
    for (int ks = 0; ks < 4; ++ks) {
      bf16x8 ea[4];
#pragma unroll
      for (int m = 0; m < 4; ++m) {
        int row = m * 16 + r16;
        ea[m] = *(const bf16x8*)((char*)eb + row * 256 + (((ks * 32 + hi * 8) * 2) ^ ((row & 7) << 4)));
      }
#pragma unroll
      for (int df = 0; df < 4; ++df) {
        bf16x8 vb8 = *(const bf16x8*)(vtb + (size_t)(df * 16 + r16) * 4096 +
                                      keybase + ks * 32 + hi * 8);
#pragma unroll
        for (int m = 0; m < 4; ++m) U[m][df] = MFMA16(ea[m], vb8, U[m][df]);
      }
    }
    __syncthreads();
  }

#pragma unroll
  for (int m = 0; m < 4; ++m)
#pragma unroll
    for (int r = 0; r < 4; ++r) {
      float v = rs[m][r];
      v += __shfl_xor(v, 1); v += __shfl_xor(v, 2);
      v += __shfl_xor(v, 4); v += __shfl_xor(v, 8);
      rs[m][r] = v;
    }
  if (r16 == 0) {
    float* rp = rspart + (((size_t)bh * 2 + chunk) * 4 + w) * 64;
#pragma unroll
    for (int m = 0; m < 4; ++m)
#pragma unroll
      for (int r = 0; r < 4; ++r) rp[m * 16 + hi * 4 + r] = rs[m][r];
  }
  float* up = Upart + (((size_t)bh * 2 + chunk) * 4 + w) * 4096;
#pragma unroll
  for (int m = 0; m < 4; ++m)
#pragma unroll
    for (int df = 0; df < 4; ++df)
#pragma unroll
      for (int r = 0; r < 4; ++r)
        up[(m * 16 + hi * 4 + r) * 64 + df * 16 + r16] = U[m][df][r];
}

// ------------- combine (blocks 0..63, 512 thr): inline T-reduce + attn2
// softmax + NS + W = A2inv @ T; blocks 64..575: w2_reduce (Cp -> W2 bf16).
__device__ __forceinline__ void mm64d(const float (*AT)[68], const float (*Bm)[68],
                                      float (*C)[68], float (*CT)[68],
                                      float alpha, float dconst, bool dmode,
                                      int tid) {
  int tr = (tid >> 4) << 1;
  int tc = (tid & 15) << 2;
  float acc[2][4] = {};
#pragma unroll 4
  for (int k = 0; k < 64; ++k) {
    float2 av = *(const float2*)&AT[k][tr];
    float4 bv = *(const float4*)&Bm[k][tc];
    float aa[2] = {av.x, av.y};
    float bb[4] = {bv.x, bv.y, bv.z, bv.w};
#pragma unroll
    for (int i = 0; i < 2; ++i)
#pragma unroll
      for (int j = 0; j < 4; ++j) acc[i][j] = fmaf(aa[i], bb[j], acc[i][j]);
  }
#pragma unroll
  for (int i = 0; i < 2; ++i)
#pragma unroll
    for (int j = 0; j < 4; ++j) {
      float vv = acc[i][j] * alpha;
      if (CT) CT[tc + j][tr + i] = vv;
      C[tr + i][tc + j] =
          dmode ? (((tr + i) == (tc + j)) ? dconst - vv : -vv) : vv;
    }
}

__global__ __launch_bounds__(512) void combine_ns_kernel(
    const float* __restrict__ Upart, const float* __restrict__ rspart,
    const float* __restrict__ qlmf, const float* __restrict__ klmf,
    u16* __restrict__ WT, const float* __restrict__ Cp,
    u16* __restrict__ W2b) {
  int tid = threadIdx.x;
  if (blockIdx.x >= 64) {  // ---- w2_reduce: 512 blocks x 512 threads
    int idx4 = (blockIdx.x - 64) * 512 + tid;
    const float4* p = (const float4*)Cp + idx4;
    float4 s = p[0];
    float4 b = p[262144], c = p[524288], d = p[786432];
    s.x += b.x + c.x + d.x;
    s.y += b.y + c.y + d.y;
    s.z += b.z + c.z + d.z;
    s.w += b.w + c.w + d.w;
    ushort4 o;
    o.x = f2bfu(s.x); o.y = f2bfu(s.y); o.z = f2bfu(s.z); o.w = f2bfu(s.w);
    ((ushort4*)W2b)[idx4] = o;
    return;
  }
  __shared__ __attribute__((aligned(16))) float A2T[64][68];
  __shared__ __attribute__((aligned(16))) float Vv[64][68];
  __shared__ __attribute__((aligned(16))) float VT[64][68];
  __shared__ __attribute__((aligned(16))) float KV[64][68];
  __shared__ __attribute__((aligned(16))) float KVT[64][68];
  __shared__ __attribute__((aligned(16))) float T2[64][68];
  __shared__ __attribute__((aligned(16))) float T4[64][68];
  __shared__ __attribute__((aligned(16))) float Tm[64][68];
  __shared__ float rsum[64], redbuf[64];
  __shared__ float scal;
  int bh = blockIdx.x;

  // Inline reduce_t: rsum then Tm = (sum of 8 U-partials)/rsum.
  if (tid < 64) {
    float s = 0.f;
    const float* rp = rspart + (size_t)bh * 512 + tid;
#pragma unroll 8
    for (int p = 0; p < 8; ++p) s += rp[p * 64];
    rsum[tid] = s;
  }
  __syncthreads();
  for (int idx4 = tid; idx4 < 1024; idx4 += 512) {
    const float4* up = (const float4*)(Upart + (size_t)bh * 32768) + idx4;
    float4 s = {0.f, 0.f, 0.f, 0.f};
#pragma unroll 8
    for (int p = 0; p < 8; ++p) {
      float4 v = up[p * 1024];
      s.x += v.x; s.y += v.y; s.z += v.z; s.w += v.w;
    }
    float inv = 1.0f / rsum[idx4 >> 4];
    int r = idx4 >> 4, c0 = (idx4 & 15) << 2;
    Tm[r][c0] = s.x * inv; Tm[r][c0 + 1] = s.y * inv;
    Tm[r][c0 + 2] = s.z * inv; Tm[r][c0 + 3] = s.w * inv;
  }
  for (int idx = tid; idx < 4096; idx += 512) {
    int r = idx >> 6, c = idx & 63;
    Vv[c][r] = qlmf[(size_t)bh * 4096 + idx];  // qlm^T
    VT[c][r] = klmf[(size_t)bh * 4096 + idx];  // klm^T
  }
  __syncthreads();
  mm64d(&Vv[0], &VT[0], &T2[0], nullptr, 1.0f, 0.f, false, tid);  // S2
  __syncthreads();
  // Parallel softmax: row = tid>>3, 8 lanes per row each covering 8 cols.
  {
    int row = tid >> 3, sub = tid & 7, cb = sub * 8;
    float mx = -1e30f;
#pragma unroll
    for (int j = 0; j < 8; ++j) mx = fmaxf(mx, T2[row][cb + j]);
    mx = fmaxf(mx, __shfl_xor(mx, 1));
    mx = fmaxf(mx, __shfl_xor(mx, 2));
    mx = fmaxf(mx, __shfl_xor(mx, 4));
    float e[8];
    float s = 0.f;
#pragma unroll
    for (int j = 0; j < 8; ++j) { e[j] = __expf(T2[row][cb + j] - mx); s += e[j]; }
    s += __shfl_xor(s, 1); s += __shfl_xor(s, 2); s += __shfl_xor(s, 4);
    float inv = 1.f / s;
#pragma unroll
    for (int j = 0; j < 8; ++j) {
      float p = e[j] * inv;
      T2[row][cb + j] = p;
      A2T[cb + j][row] = p;
    }
  }
  __syncthreads();
  // V0 = max colsum (softmax entries positive); VI = max rowsum = 1 exactly.
  {
    int col = tid >> 3, sub = tid & 7;
    float cs = 0.f;
#pragma unroll
    for (int j = 0; j < 8; ++j) cs += T2[sub * 8 + j][col];
    cs += __shfl_xor(cs, 1); cs += __shfl_xor(cs, 2); cs += __shfl_xor(cs, 4);
    if (sub == 0) redbuf[col] = cs;
  }
  __syncthreads();
  if (tid < 64) {
    float v0 = redbuf[tid];
#pragma unroll
    for (int m = 1; m < 64; m <<= 1) v0 = fmaxf(v0, __shfl_xor(v0, m));
    if (tid == 0) scal = 1.0f / v0;
  }
  __syncthreads();
  for (int idx = tid; idx < 4096; idx += 512) {
    int r = idx >> 6, c = idx & 63;
    Vv[r][c] = A2T[r][c] * scal;  // V0 = A2^T / (V0*VI), VI == 1
    VT[r][c] = T2[r][c] * scal;   // V0^T
  }
  __syncthreads();
  float (*Vt_r)[68] = VT;
  float (*Vt_w)[68] = KV;
#pragma unroll 1
  for (int it = 0; it < 6; ++it) {
    mm64d(&A2T[0], &Vv[0], &T2[0], &KVT[0], 1.0f, 7.0f, true, tid);
    __syncthreads();
    mm64d(&KVT[0], &T2[0], &T4[0], nullptr, 1.0f, 15.0f, true, tid);
    __syncthreads();
    mm64d(&KVT[0], &T4[0], &T2[0], nullptr, 1.0f, 13.0f, true, tid);
    __syncthreads();
    mm64d(Vt_r, &T2[0], &Vv[0], Vt_w, 0.25f, 0.f, false, tid);
    __syncthreads();
    float (*tmp)[68] = Vt_r; Vt_r = Vt_w; Vt_w = tmp;
  }
  mm64d(Vt_r, &Tm[0], &T2[0], nullptr, 1.0f, 0.f, false, tid);  // W = A2inv @ T
  __syncthreads();
  for (int idx = tid; idx < 4096; idx += 512) {
    int r = idx >> 6, c = idx & 63;
    WT[(size_t)bh * 4096 + c * 64 + r] = f2bfu(T2[r][c]);  // store W^T bf16
  }
}

// ------------------- final: softmax(q @ klm^T) @ W  ->  attn_out (B,N,C) bf16
__global__ __launch_bounds__(256) void attn1_out_kernel(
    const u16* __restrict__ Q, const u16* __restrict__ klmb,
    const u16* __restrict__ WT, u16* __restrict__ AO) {
  __shared__ __attribute__((aligned(16))) u16 Elds[4][2048];  // per-wave 32x64 bf16
  int bh = blockIdx.y;
  int b = bh >> 4, h = bh & 15;
  int tid = threadIdx.x, lane = tid & 63, w = tid >> 6;
  int r16 = lane & 15, hi = lane >> 4;
  int rowbase = blockIdx.x * 128 + w * 32;
  const u16* qb = Q + ((size_t)bh * 4096 + rowbase) * 64;
  const u16* kb = klmb + (size_t)bh * 4096;
  const u16* wtb = WT + (size_t)bh * 4096;
  u16* eb = &Elds[w][0];
  f32x4 z4 = {0.f, 0.f, 0.f, 0.f};

  bf16x8 afr[2][2];
#pragma unroll
  for (int mi = 0; mi < 2; ++mi)
#pragma unroll
    for (int kk = 0; kk < 2; ++kk)
      afr[mi][kk] = *(const bf16x8*)(qb + (mi * 16 + r16) * 64 + kk * 32 + hi * 8);

  float rs[2][4] = {};
  for (int cf = 0; cf < 4; ++cf) {
    f32x4 S[2] = {z4, z4};
#pragma unroll
    for (int kk = 0; kk < 2; ++kk) {
      bf16x8 bfr = *(const bf16x8*)(kb + (cf * 16 + r16) * 64 + kk * 32 + hi * 8);
#pragma unroll
      for (int mi = 0; mi < 2; ++mi) S[mi] = MFMA16(afr[mi][kk], bfr, S[mi]);
    }
#pragma unroll
    for (int mi = 0; mi < 2; ++mi)
#pragma unroll
      for (int r = 0; r < 4; ++r) {
        float e = __expf(S[mi][r]);
        rs[mi][r] += e;
        int row = mi * 16 + hi * 4 + r;
        int key = cf * 16 + r16;
        *(u16*)((char*)eb + row * 128 + ((key * 2) ^ ((row & 7) << 4))) = f2bfu(e);
      }
  }
#pragma unroll
  for (int mi = 0; mi < 2; ++mi)
#pragma unroll
    for (int r = 0; r < 4; ++r) {
      float v = rs[mi][r];
      v += __shfl_xor(v, 1); v += __shfl_xor(v, 2);
      v += __shfl_xor(v, 4); v += __shfl_xor(v, 8);
      rs[mi][r] = v;
    }
  __syncthreads();

  f32x4 O[2][4];
#pragma unroll
  for (int mi = 0; mi < 2; ++mi)
#pragma unroll
    for (int df = 0; df < 4; ++df) O[mi][df] = z4;
  for (int ks = 0; ks < 2; ++ks) {
    bf16x8 ea[2];
#pragma unroll
    for (int mi = 0; mi < 2; ++mi) {
      int row = mi * 16 + r16;
      ea[mi] = *(const bf16x8*)((char*)eb + row * 128 + (((ks * 32 + hi * 8) * 2) ^ ((row & 7) << 4)));
    }
#pragma unroll
    for (int df = 0; df < 4; ++df) {
      bf16x8 wfr = *(const bf16x8*)(wtb + (df * 16 + r16) * 64 + ks * 32 + hi * 8);
#pragma unroll
      for (int mi = 0; mi < 2; ++mi) O[mi][df] = MFMA16(ea[mi], wfr, O[mi][df]);
    }
  }
#pragma unroll
  for (int mi = 0; mi < 2; ++mi)
#pragma unroll
    for (int df = 0; df < 4; ++df)
#pragma unroll
      for (int r = 0; r < 4; ++r) {
        int row = mi * 16 + hi * 4 + r;
        int n = rowbase + row;
        int col = h * 64 + df * 16 + r16;
        float val = O[mi][df][r] / rs[mi][r];
        AO[((size_t)b * 4096 + n) * 1024 + col] = f2bfu(val);
      }
}

// ---------------------------------------------------------------- launcher
extern "C" void kernel_launch(void* const* d_in, const int* in_sizes, int n_in,
                              void* d_out, int out_size, void* d_ws, size_t ws_size,
                              hipStream_t stream) {
  (void)in_sizes; (void)n_in; (void)out_size; (void)ws_size;
  const float* x       = (const float*)d_in[0];
  const float* ln_w    = (const float*)d_in[1];
  const float* ln_b    = (const float*)d_in[2];
  const float* qkv_w   = (const float*)d_in[3];
  const float* qkv_b   = (const float*)d_in[4];
  const float* gamma_w = (const float*)d_in[5];
  const float* gamma_b = (const float*)d_in[6];
  const float* proj_w  = (const float*)d_in[7];
  const float* proj_b  = (const float*)d_in[8];

  char* ws = (char*)d_ws;
  u16* XN     = (u16*)(ws + 0);           // xn; UP[0,16M)+CPF[16.7M,33.5M); AO
  u16* Qb     = (u16*)(ws + 33554432);
  u16* Kb     = (u16*)(ws + 67108864);    // K (dead after attn3)
  u16* Vb     = (u16*)(ws + 100663296);   // V^T; W2b overlay after attn3
  u16* QKVW   = (u16*)(ws + 134217728);
  u16* GTb    = (u16*)(ws + 140509184);   // gamma^T bf16
  u16* PW     = (u16*)(ws + 142606336);
  float* QLMF = (float*)(ws + 144703488);
  float* KLMF = (float*)(ws + 145752064);
  u16* QLMB   = (u16*)(ws + 146800640);
  u16* KLMB   = (u16*)(ws + 147324928);
  float* RSP  = (float*)(ws + 147849216); // 128KB used
  float* B2F  = (float*)(ws + 148111360); // 4KB (RSP region upper half)
  u16* WTb    = (u16*)(ws + 148373504);
  float* UP   = (float*)XN;               // xn dead after qkv GEMM
  float* CPF  = (float*)(ws + 16777216);  // written attn3-launch (xn dead)
  u16* W2b    = (u16*)(ws + 102760448);   // on Vb (dead after attn3)

  prep_kernel<<<18692, 256, 0, stream>>>(x, ln_w, ln_b, XN, qkv_w, QKVW,
                                         proj_w, PW, gamma_w, GTb,
                                         gamma_b, proj_b, B2F);
  gemm_bt<2><<<dim3(12, 64), 512, 0, stream>>>(XN, QKVW, qkv_b, nullptr, nullptr,
                                               Qb, Kb, Vb, QLMF, QLMB, KLMF, KLMB,
                                               16384, 3072, 1024);
  attn3_pv_kernel<<<dim3(6, 64), 256, 0, stream>>>(QLMB, Kb, Vb, UP, RSP,
                                                   PW, GTb, CPF);
  combine_ns_kernel<<<576, 512, 0, stream>>>(UP, RSP, QLMF, KLMF, WTb, CPF, W2b);
  attn1_out_kernel<<<dim3(32, 64), 256, 0, stream>>>(Qb, KLMB, WTb, XN);
  gemm_bt<1><<<dim3(4, 64), 512, 0, stream>>>(
      XN, W2b, B2F, (float*)d_out, nullptr, nullptr, nullptr, nullptr,
      nullptr, nullptr, nullptr, nullptr,
      16384, 1024, 1024);
}